// Round 9
// baseline (131.175 us; speedup 1.0000x reference)
//
#include <hip/hip_runtime.h>

#define LN 8192           // 8194 - 2
#define B_ROWS 4096
#define NMEANS 6

#define COLS_PER_BLOCK 1024   // 256 threads * 4 floats
#define ROWS_PER_BLOCK 64
#define COL_SEGS (LN / COLS_PER_BLOCK)        // 8
#define ROW_CHUNKS (B_ROWS / ROWS_PER_BLOCK)  // 64

typedef float v4f __attribute__((ext_vector_type(4)));

// ---------------------------------------------------------------------------
// Kernel A (CONTROL — identical to R8 best, 26.0 us): correct output.
// ---------------------------------------------------------------------------
__global__ void __launch_bounds__(256)
fused_kernel(const float* __restrict__ w, float* __restrict__ out) {
    const int bid     = blockIdx.x;
    const int colSeg  = bid & (COL_SEGS - 1);        // 0..7
    const int rowBase = (bid >> 3) * ROWS_PER_BLOCK; // 0..4032 step 64

    const int j0 = colSeg * COLS_PER_BLOCK + threadIdx.x * 4;

    const float bk[NMEANS] = {1.99471140f, 1.20985428f, 0.26995483f,
                              0.02215925f, 6.69151e-4f, 7.43360e-6f};
    float a[NMEANS];
#pragma unroll
    for (int k = 0; k < NMEANS; ++k) a[k] = w[k] * bk[k];

    v4f v;
#pragma unroll
    for (int e = 0; e < 4; ++e) {
        float u = (float)(j0 + e) * (5.0f / (float)LN);
        float g = __expf(-0.5f * u * u);
        float E = __expf(u);
        float h = a[5];
        h = h * E + a[4];
        h = h * E + a[3];
        h = h * E + a[2];
        h = h * E + a[1];
        h = h * E + a[0];
        v[e] = g * h;
    }

    float* base = out + (long long)rowBase * LN + j0;
#pragma unroll
    for (int r = 0; r < ROWS_PER_BLOCK; ++r) {
        *(v4f*)(base + (long long)r * LN) = v;
    }
}

// ---------------------------------------------------------------------------
// Kernel B (DIAGNOSTIC): identical tiled store pattern writing `nrows` rows
// of constants into d_ws. Sized ~512 MB so it (a) matches the 537 MB rocclr
// fills that run at ~7 TB/s and (b) appears in rocprof top-5 with counters.
// Deterministic constant writes each call; no state is read.
// ---------------------------------------------------------------------------
__global__ void __launch_bounds__(256)
probe_fill_kernel(float* __restrict__ ws, int nrows) {
    const int bid     = blockIdx.x;
    const int colSeg  = bid & (COL_SEGS - 1);
    const int rowChunk = bid >> 3;                   // 0..255 (2048 blocks)

    const int j0 = colSeg * COLS_PER_BLOCK + threadIdx.x * 4;
    const v4f v = {1.0f, 1.0f, 1.0f, 1.0f};

    const int rowBase = rowChunk * ROWS_PER_BLOCK;   // 0..16320 step 64
    if (rowBase >= nrows) return;
    const int rend = (rowBase + ROWS_PER_BLOCK < nrows) ? ROWS_PER_BLOCK
                                                        : (nrows - rowBase);
    float* base = ws + (long long)rowBase * LN + j0;
    for (int r = 0; r < rend; ++r) {
        *(v4f*)(base + (long long)r * LN) = v;
    }
}

extern "C" void kernel_launch(void* const* d_in, const int* in_sizes, int n_in,
                              void* d_out, int out_size, void* d_ws, size_t ws_size,
                              hipStream_t stream) {
    const float* w = (const float*)d_in[0];   // weights [6]
    float* out = (float*)d_out;

    // A: correct output (control, identical to R8)
    fused_kernel<<<dim3(COL_SEGS * ROW_CHUNKS), dim3(256), 0, stream>>>(w, out);

    // B: large-scale store-pattern probe into workspace (guarded by ws_size)
    long long avail_rows = (long long)(ws_size / (LN * sizeof(float)));
    int nrows = (int)(avail_rows < 16384 ? avail_rows : 16384); // cap 512 MB
    if (nrows > 0) {
        probe_fill_kernel<<<dim3(2048), dim3(256), 0, stream>>>((float*)d_ws,
                                                                nrows);
    }
}